// Round 13
// baseline (341.761 us; speedup 1.0000x reference)
//
#include <hip/hip_runtime.h>
#include <hip/hip_bf16.h>

// Linformer attention, MI355X.
//   EX_b = We @ X_b          (split-K=4, fp32 partials + reduce, 2-phase core)
//   [kp|vpT]_b = EX_b @ [Wk|Wv]^T + be   (fused GEMM, dual-layout epilogue)
//   Q = X @ Wq^T  (gemm8p: 256^2 8-phase counted-vmcnt); attn fused
//   (2 row-groups/wave); out = O @ Wo^T + bo (gemm8p, fp32+bias).
// B=8, N=4096, DIM=1024, H=16, DH=64, P=256.

typedef unsigned short bf16u;
typedef __attribute__((ext_vector_type(8))) short short8;   // 8 bf16 in 4 VGPRs
typedef __attribute__((ext_vector_type(4))) float f32x4;

__device__ __forceinline__ unsigned short f2bf(float f) {
    unsigned u = __float_as_uint(f);
    u += 0x7FFF + ((u >> 16) & 1);          // round-to-nearest-even
    return (unsigned short)(u >> 16);
}

__device__ __forceinline__ f32x4 mfma16(short8 a, short8 b, f32x4 c) {
    return __builtin_amdgcn_mfma_f32_16x16x32_bf16(a, b, c, 0, 0, 0);
}

#define AS1 __attribute__((address_space(1)))
#define AS3 __attribute__((address_space(3)))

// ---------------------------------------------------------------- fp32 -> bf16
__global__ void cvt_kernel(const float* __restrict__ in, bf16u* __restrict__ out, int n4) {
    int i = blockIdx.x * blockDim.x + threadIdx.x;
    int stride = gridDim.x * blockDim.x;
    for (int j = i; j < n4; j += stride) {
        float4 v = ((const float4*)in)[j];
        union { bf16u s[4]; uint2 u; } o;
        o.s[0] = f2bf(v.x); o.s[1] = f2bf(v.y); o.s[2] = f2bf(v.z); o.s[3] = f2bf(v.w);
        ((uint2*)out)[j] = o.u;
    }
}

// ------------------------- fused cvt + 64x64 tiled transpose of x ------------
__global__ __launch_bounds__(256) void cvt_transpose_x(const float* __restrict__ x,
                                                       bf16u* __restrict__ Xbf,
                                                       bf16u* __restrict__ XT) {
    __shared__ bf16u T[64][72];                  // [c-local][n-local], pad 8
    const int b = blockIdx.z;
    const int n0 = blockIdx.y * 64, c0 = blockIdx.x * 64;
    const int t = threadIdx.x;
    const int cx = t & 15, ry = t >> 4;
#pragma unroll
    for (int p = 0; p < 4; p++) {
        const int nn = p * 16 + ry;
        const size_t g = ((size_t)b * 4096 + n0 + nn) * 1024 + c0 + cx * 4;
        float4 v = *(const float4*)&x[g];
        union { bf16u s[4]; uint2 u; } o;
        o.s[0] = f2bf(v.x); o.s[1] = f2bf(v.y); o.s[2] = f2bf(v.z); o.s[3] = f2bf(v.w);
        *(uint2*)&Xbf[g] = o.u;
#pragma unroll
        for (int j = 0; j < 4; j++) T[cx * 4 + j][nn] = o.s[j];
    }
    __syncthreads();
    const int cc = t >> 2, ch = t & 3;
#pragma unroll
    for (int j = 0; j < 2; j++) {
        const int nch = ch + j * 4;
        short8 vv = *(const short8*)&T[cc][nch * 8];
        *(short8*)&XT[((size_t)b * 1024 + c0 + cc) * 4096 + n0 + nch * 8] = vv;
    }
}

// --------------------- 128x128 / BK=64 2-phase double-buffered GEMM core
// 4 waves (2x2), per-wave 64x64. LDS 2 x (A 16KB | B 16KB) = 64KB -> 2
// blocks/CU. Per K-tile: issue next tile's 8 global_load_lds FIRST, then
// 16 ds_read_b128 + 32 MFMA, then ONE __syncthreads (drains vmcnt: prefetch
// had the whole compute phase to land). Swizzle gp ^= (row&7) both sides
// (rule #21): 8 positions/16 rows -> 2-way aliasing = free (m136).
// K-accumulation order per output element identical to the old BK=32 core.
__device__ __forceinline__ void gemm_core2(const bf16u* __restrict__ Ablk, int ldA,
                                           const bf16u* __restrict__ Bblk, int ldB,
                                           int Kiter, f32x4 (&acc)[4][4]) {
    __shared__ __align__(16) bf16u As[2][8192];
    __shared__ __align__(16) bf16u Bs[2][8192];
    const int t = threadIdx.x;
    const int wave = t >> 6, lane = t & 63;
    const int wm = (wave >> 1) * 64, wn = (wave & 1) * 64;
    const int lr = lane & 15, g4 = lane >> 4;

    auto STAGE = [&](int buf, int kt) {
#pragma unroll
        for (int i = 0; i < 4; i++) {
            const int c = i * 256 + t;                 // granule 0..1023
            const int row = c >> 3, gp = c & 7;
            const int col = kt * 64 + ((gp ^ (row & 7)) << 3);
            __builtin_amdgcn_global_load_lds(
                (const AS1 unsigned*)(Ablk + (size_t)row * ldA + col),
                (AS3 unsigned*)(&As[buf][c * 8]), 16, 0, 0);
            __builtin_amdgcn_global_load_lds(
                (const AS1 unsigned*)(Bblk + (size_t)row * ldB + col),
                (AS3 unsigned*)(&Bs[buf][c * 8]), 16, 0, 0);
        }
    };

    const int nkt = Kiter >> 6;
    STAGE(0, 0);
    __syncthreads();
    for (int kt = 0; kt < nkt; kt++) {
        const int buf = kt & 1;
        if (kt + 1 < nkt) STAGE(buf ^ 1, kt + 1);     // issue-early (T3 minimum)
        short8 a[4][2], b[4][2];
#pragma unroll
        for (int mi = 0; mi < 4; mi++) {
            const int row = wm + mi * 16 + lr;
#pragma unroll
            for (int ks = 0; ks < 2; ks++) {
                const int gp = (ks * 4 + g4) ^ (row & 7);
                a[mi][ks] = *(const short8*)&As[buf][row * 64 + gp * 8];
            }
        }
#pragma unroll
        for (int ni = 0; ni < 4; ni++) {
            const int row = wn + ni * 16 + lr;
#pragma unroll
            for (int ks = 0; ks < 2; ks++) {
                const int gp = (ks * 4 + g4) ^ (row & 7);
                b[ni][ks] = *(const short8*)&Bs[buf][row * 64 + gp * 8];
            }
        }
#pragma unroll
        for (int ks = 0; ks < 2; ks++)                 // ks outer: k-order 0,32,...
#pragma unroll
            for (int mi = 0; mi < 4; mi++)
#pragma unroll
                for (int ni = 0; ni < 4; ni++)
                    acc[mi][ni] = mfma16(a[mi][ks], b[ni][ks], acc[mi][ni]);
        __syncthreads();                               // one barrier per K-tile
    }
}

// ---------------------- EX split-K: partial[ks][b][p][c] (fp32), K-slice 1024
__global__ __launch_bounds__(256, 2) void gemm_ex_splitk(const bf16u* __restrict__ We,
                                                         const bf16u* __restrict__ XT,
                                                         float* __restrict__ Cpart) {
    const int bn = blockIdx.x, bm = blockIdx.y;
    const int bz = blockIdx.z >> 2, ks = blockIdx.z & 3;
    f32x4 acc[4][4];
#pragma unroll
    for (int i = 0; i < 4; i++)
#pragma unroll
        for (int j = 0; j < 4; j++) acc[i][j] = f32x4{0.f, 0.f, 0.f, 0.f};

    gemm_core2(We + (size_t)bm * 128 * 4096 + ks * 1024, 4096,
               XT + ((size_t)bz * 1024 + bn * 128) * 4096 + ks * 1024, 4096,
               1024, acc);

    const int lane = threadIdx.x & 63, wave = threadIdx.x >> 6;
    const int wm = (wave >> 1) * 64, wn = (wave & 1) * 64;
    const int lr = lane & 15, lg = (lane >> 4) * 4;
    float* Cp = Cpart + (size_t)(ks * 8 + bz) * 256 * 1024;
#pragma unroll
    for (int ni = 0; ni < 4; ni++) {
        const int col = bn * 128 + wn + ni * 16 + lr;
#pragma unroll
        for (int mi = 0; mi < 4; mi++) {
#pragma unroll
            for (int r = 0; r < 4; r++) {
                const int row = bm * 128 + wm + mi * 16 + lg + r;
                Cp[(size_t)row * 1024 + col] = acc[mi][ni][r];
            }
        }
    }
}

// -------------------- reduce 4 fp32 partials -> bf16 EX (2M elements)
__global__ __launch_bounds__(256) void reduce4_cvt(const float* __restrict__ P,
                                                   bf16u* __restrict__ out) {
    const int j = blockIdx.x * blockDim.x + threadIdx.x;
    const float4* p = (const float4*)P;
    float4 s0 = p[j], s1 = p[j + 524288], s2 = p[j + 1048576], s3 = p[j + 1572864];
    union { bf16u s[4]; uint2 u; } o;
    o.s[0] = f2bf((s0.x + s1.x) + (s2.x + s3.x));
    o.s[1] = f2bf((s0.y + s1.y) + (s2.y + s3.y));
    o.s[2] = f2bf((s0.z + s1.z) + (s2.z + s3.z));
    o.s[3] = f2bf((s0.w + s1.w) + (s2.w + s3.w));
    ((uint2*)out)[j] = o.u;
}

// ----------- fused kp/vpT GEMM: Y_b = EX_b @ [Wk|Wv]^T + be, dual epilogue
__global__ __launch_bounds__(256, 2) void gemm_kpv(const bf16u* __restrict__ EX,
                                                   const bf16u* __restrict__ Wkv,
                                                   const float* __restrict__ be,
                                                   bf16u* __restrict__ kp,
                                                   bf16u* __restrict__ vpT) {
    const int bn = blockIdx.x, bm = blockIdx.y, bz = blockIdx.z;
    f32x4 acc[4][4];
#pragma unroll
    for (int i = 0; i < 4; i++)
#pragma unroll
        for (int j = 0; j < 4; j++) acc[i][j] = f32x4{0.f, 0.f, 0.f, 0.f};

    gemm_core2(EX + (size_t)bz * 256 * 1024 + (size_t)bm * 128 * 1024, 1024,
               Wkv + (size_t)bn * 128 * 1024, 1024, 1024, acc);

    const int lane = threadIdx.x & 63, wave = threadIdx.x >> 6;
    const int wm = (wave >> 1) * 64, wn = (wave & 1) * 64;
    const int lr = lane & 15, lg = (lane >> 4) * 4;
    bf16u* kpB = kp + (size_t)bz * 256 * 1024;
    bf16u* vpB = vpT + (size_t)bz * 1024 * 256;
    const int ebase = bn * 128 + wn;
#pragma unroll
    for (int ni = 0; ni < 4; ni++) {
        const int col = ebase + ni * 16 + lr;
        const int region = (ebase + ni * 16) >> 10;
#pragma unroll
        for (int mi = 0; mi < 4; mi++) {
            const int p0 = bm * 128 + wm + mi * 16 + lg;
            if (region == 0) {
#pragma unroll
                for (int r = 0; r < 4; r++)
                    kpB[(size_t)(p0 + r) * 1024 + col] = f2bf(acc[mi][ni][r] + be[p0 + r]);
            } else {
                const int d = col - 1024;
                union { bf16u s[4]; uint2 u; } o;
#pragma unroll
                for (int r = 0; r < 4; r++) o.s[r] = f2bf(acc[mi][ni][r] + be[p0 + r]);
                *(uint2*)&vpB[(size_t)d * 256 + p0] = o.u;
            }
        }
    }
}

// -------- 256x256 / BK=64 / 8-wave (2M x 4N), 8-phase counted-vmcnt GEMM
// (verbatim round-9 kernel -- best measured structure for the big GEMMs)
template<int MODE>
__global__ __launch_bounds__(512, 2) void gemm8p(const bf16u* __restrict__ A,
                                                 const bf16u* __restrict__ Bt,
                                                 const float* __restrict__ bias,
                                                 void* __restrict__ Cout,
                                                 int K) {
    __shared__ __align__(16) bf16u L[2][32768];   // [buf]: A[256][64] | B[256][64]

    const int nwg = gridDim.x;                    // multiple of 8
    const int bid = blockIdx.x;
    const int logical = (bid & 7) * (nwg >> 3) + (bid >> 3);
    const int bn = logical & 3, bm = logical >> 2;

    const bf16u* Ablk = A + (size_t)bm * 256 * K;
    const bf16u* Bblk = Bt + (size_t)bn * 256 * K;

    const int t = threadIdx.x;
    const int wid = t >> 6, lane = t & 63;
    const int wm = (wid >> 2) * 128, wn = (wid & 3) * 64;   // per-wave 128x64 out
    const int lr = lane & 15, g4 = lane >> 4;

    f32x4 acc[8][4];
#pragma unroll
    for (int i = 0; i < 8; i++)
#pragma unroll
        for (int j = 0; j < 4; j++) acc[i][j] = f32x4{0.f, 0.f, 0.f, 0.f};

    auto STAGE = [&](int buf, int which, int half, int kt) {
#pragma unroll
        for (int i = 0; i < 2; i++) {
            const int c = i * 512 + t;
            const int row = half * 128 + (c >> 3);
            const int gp = c & 7;
            const int col = kt * 64 + ((gp ^ (row & 7)) << 3);
            const bf16u* src = (which ? Bblk : Ablk) + (size_t)row * K + col;
            __builtin_amdgcn_global_load_lds((const AS1 unsigned*)src,
                (AS3 unsigned*)(&L[buf][which * 16384 + half * 8192 + c * 8]), 16, 0, 0);
        }
    };

    short8 aF[4][2], bE[2][2], bO[2][2];
    auto LDA = [&](int buf, int mq) {
#pragma unroll
        for (int mi = 0; mi < 4; mi++) {
            const int row = wm + mq * 64 + mi * 16 + lr;
#pragma unroll
            for (int ks = 0; ks < 2; ks++) {
                const int gp = (ks * 4 + g4) ^ (row & 7);
                aF[mi][ks] = *(const short8*)&L[buf][row * 64 + gp * 8];
            }
        }
    };
    auto LDB = [&](int buf, int nq, short8 (&bF)[2][2]) {
#pragma unroll
        for (int ni = 0; ni < 2; ni++) {
            const int row = wn + nq * 32 + ni * 16 + lr;
#pragma unroll
            for (int ks = 0; ks < 2; ks++) {
                const int gp = (ks * 4 + g4) ^ (row & 7);
                bF[ni][ks] = *(const short8*)&L[buf][16384 + row * 64 + gp * 8];
            }
        }
    };
    auto MM = [&](int mq, int nq, short8 (&bF)[2][2]) {
        __builtin_amdgcn_s_setprio(1);
#pragma unroll
        for (int mi = 0; mi < 4; mi++)
#pragma unroll
            for (int nj = 0; nj < 2; nj++)
#pragma unroll
                for (int ks = 0; ks < 2; ks++)
                    acc[mq * 4 + mi][nq * 2 + nj] =
                        mfma16(aF[mi][ks], bF[nj][ks], acc[mq * 4 + mi][nq * 2 + nj]);
        __builtin_amdgcn_s_setprio(0);
    };
    auto BAR = [&]() {
        asm volatile("" ::: "memory");
        __builtin_amdgcn_s_barrier();
        asm volatile("" ::: "memory");
    };
    auto LGKM0 = [&]() {
        asm volatile("s_waitcnt lgkmcnt(0)" ::: "memory");
        __builtin_amdgcn_sched_barrier(0);
    };

    const int nkt = K >> 6;
    const int niter = nkt >> 1;

    STAGE(0, 0, 0, 0); STAGE(0, 0, 1, 0); STAGE(0, 1, 0, 0); STAGE(0, 1, 1, 0);
    STAGE(1, 0, 0, 1); STAGE(1, 0, 1, 1); STAGE(1, 1, 0, 1); STAGE(1, 1, 1, 1);
    asm volatile("s_waitcnt vmcnt(8)" ::: "memory");
    BAR();

    for (int it = 0; it < niter; it++) {
        const int kt1 = 2 * it + 1, kt2 = 2 * it + 2, kt3 = 2 * it + 3;
        const bool p123 = (it > 0), s4 = (kt2 < nkt), s8 = (kt3 < nkt);

        LDA(0, 0); LDB(0, 0, bE);
        if (p123) STAGE(1, 0, 1, kt1);
        asm volatile("s_waitcnt lgkmcnt(8)" ::: "memory");
        BAR(); LGKM0();
        MM(0, 0, bE);
        BAR();
        LDB(0, 1, bO);
        if (p123) STAGE(1, 1, 0, kt1);
        BAR(); LGKM0();
        MM(0, 1, bO);
        BAR();
        LDA(0, 1);
        if (p123) STAGE(1, 1, 1, kt1);
        BAR(); LGKM0();
        MM(1, 1, bO);
        BAR();
        if (s4) STAGE(0, 0, 0, kt2);
        MM(1, 0, bE);
        if (s4) asm volatile("s_waitcnt vmcnt(2)" ::: "memory");
        else    asm volatile("s_waitcnt vmcnt(0)" ::: "memory");
        BAR();

        LDA(1, 0); LDB(1, 0, bE);
        if (s4) STAGE(0, 0, 1, kt2);
        asm volatile("s_waitcnt lgkmcnt(8)" ::: "memory");
        BAR(); LGKM0();
        MM(0, 0, bE);
        BAR();
        LDB(1, 1, bO);
        if (s4) STAGE(0, 1, 0, kt2);
        BAR(); LGKM0();
        MM(0, 1, bO);
        BAR();
        LDA(1, 1);
        if (s4) STAGE(0, 1, 1, kt2);
        BAR(); LGKM0();
        MM(1, 1, bO);
        BAR();
        if (s8) STAGE(1, 0, 0, kt3);
        MM(1, 0, bE);
        if (s8) asm volatile("s_waitcnt vmcnt(2)" ::: "memory");
        else    asm volatile("s_waitcnt vmcnt(0)" ::: "memory");
        BAR();
    }

    const int lg = g4 * 4;
    if (MODE == 0) {
        bf16u* C = (bf16u*)Cout;
#pragma unroll
        for (int mi = 0; mi < 8; mi++) {
#pragma unroll
            for (int r = 0; r < 4; r++) {
                const size_t row = (size_t)bm * 256 + wm + mi * 16 + lg + r;
#pragma unroll
                for (int ni = 0; ni < 4; ni++)
                    C[row * 1024 + bn * 256 + wn + ni * 16 + lr] = f2bf(acc[mi][ni][r]);
            }
        }
    } else {
        float* C = (float*)Cout;
        float bv[4];
#pragma unroll
        for (int ni = 0; ni < 4; ni++) bv[ni] = bias[bn * 256 + wn + ni * 16 + lr];
#pragma unroll
        for (int mi = 0; mi < 8; mi++) {
#pragma unroll
            for (int r = 0; r < 4; r++) {
                const size_t row = (size_t)bm * 256 + wm + mi * 16 + lg + r;
#pragma unroll
                for (int ni = 0; ni < 4; ni++)
                    C[row * 1024 + bn * 256 + wn + ni * 16 + lr] = acc[mi][ni][r] + bv[ni];
            }
        }
    }
}

// ---------------------------------------------------- K3: fused attention
// (unchanged from round 10 -- 2 row-groups per wave, Ks-fragment reuse)
__global__ __launch_bounds__(256, 2) void attn_kernel(const bf16u* __restrict__ Q,
                                                      const bf16u* __restrict__ kp,
                                                      const bf16u* __restrict__ vpT,
                                                      bf16u* __restrict__ O) {
    __shared__ __align__(16) bf16u S[32768];     // [0,16384): Ks / P overlay; [16384,32768): Vs
    const int bh = blockIdx.y, b = bh >> 4, h = bh & 15;
    const int t = threadIdx.x;
    const int wave = t >> 6, lane = t & 63;
    const int lr = lane & 15, g = lane >> 4;
    const int i0 = blockIdx.x * 128 + wave * 16;          // G0 rows; G1 = +64
    const size_t mrow = (size_t)b * 4096 + i0;

    short8 bq0[2], bq1[2];
    const bf16u* Qb0 = Q + (mrow + lr) * 1024 + h * 64 + g * 8;
    bq0[0] = *(const short8*)&Qb0[0];
    bq0[1] = *(const short8*)&Qb0[32];
    const bf16u* Qb1 = Qb0 + (size_t)64 * 1024;
    bq1[0] = *(const short8*)&Qb1[0];
    bq1[1] = *(const short8*)&Qb1[32];

    const bf16u* kpb = kp + ((size_t)b * 256) * 1024 + h * 64;
    const bf16u* vpb = vpT + ((size_t)b * 1024 + h * 64) * 256;
#pragma unroll
    for (int i = 0; i < 8; i++) {
        const int c = i * 256 + t;
        const int ubase = (i * 256 + wave * 64) * 8;
        {
            const int p = c >> 3, d8 = (c & 7) ^ (p & 7);
            __builtin_amdgcn_global_load_lds(
                (const AS1 unsigned*)(kpb + (size_t)p * 1024 + d8 * 8),
                (AS3 unsigned*)&S[ubase], 16, 0, 0);
        }
        {
            const int d = c >> 5, p8 = (c & 31) ^ (d & 15);
            __builtin_amdgcn_global_load_lds(
                (const AS1 unsigned*)(vpb + (size_t)d * 256 + p8 * 8),
                (AS3 unsigned*)&S[16384 + ubase], 16, 0, 0);
        }
    }
    __syncthreads();

    f32x4 d0[16], d1[16];
#pragma unroll
    for (int pj = 0; pj < 16; pj++) { d0[pj] = f32x4{0.f,0.f,0.f,0.f}; d1[pj] = f32x4{0.f,0.f,0.f,0.f}; }
    __builtin_amdgcn_s_setprio(1);
#pragma unroll
    for (int pj = 0; pj < 16; pj++) {
#pragma unroll
        for (int kk = 0; kk < 2; kk++) {
            const int gr = (pj * 16 + lr) * 8 + ((kk * 4 + g) ^ (lr & 7));
            short8 ak = *(const short8*)&S[gr * 8];
            d0[pj] = mfma16(ak, bq0[kk], d0[pj]);
            d1[pj] = mfma16(ak, bq1[kk], d1[pj]);
        }
    }
    __builtin_amdgcn_s_setprio(0);

    float s0 = 0.f;
#pragma unroll
    for (int pj = 0; pj < 16; pj++) {
#pragma unroll
        for (int r = 0; r < 4; r++) {
            float e = __expf(d0[pj][r] * 0.125f);
            d0[pj][r] = e;
            s0 += e;
        }
    }
    s0 += __shfl_xor(s0, 16);
    s0 += __shfl_xor(s0, 32);
    const float inv0 = 1.0f / s0;
    float invO0[4];
#pragma unroll
    for (int r = 0; r < 4; r++) invO0[r] = __shfl(inv0, g * 4 + r);

    unsigned pkw0[16][2];
#pragma unroll
    for (int pj = 0; pj < 16; pj++) {
        asm("v_cvt_pk_bf16_f32 %0, %1, %2" : "=v"(pkw0[pj][0]) : "v"(d0[pj][0]), "v"(d0[pj][1]));
        asm("v_cvt_pk_bf16_f32 %0, %1, %2" : "=v"(pkw0[pj][1]) : "v"(d0[pj][2]), "v"(d0[pj][3]));
    }

    __syncthreads();

    const int pbase = wave * 4096 + lr * 256;
    const int pxor = (lr & 7) << 3;
#pragma unroll
    for (int pj = 0; pj < 16; pj++) {
        const int el = (pbase + pj * 16 + g * 4) ^ pxor;
        uint2 u; u.x = pkw0[pj][0]; u.y = pkw0[pj][1];
        *(uint2*)&S[el] = u;
    }

    float s1 = 0.f;
#pragma unroll
    for (int pj = 0; pj < 16; pj++) {
#pragma unroll
        for (int r = 0; r < 4; r++) {
            float e = __expf(d1[pj][r] * 0.125f);
            d1[pj][r] = e;
            s1 += e;
        }
    }
    s1 += __shfl_xor(s1, 16);
    s1 += __shfl_xor(s1, 32);
    const float inv1 = 1.0f / s1;
    float invO1[4];
#pragma unroll
    for (int r = 0; r < 4; r++) invO1[r] = __shfl(inv1, g * 4 + r);
    unsigned pkw1[16][2];
#pragma unroll
    for (int pj = 0; pj < 16; pj++) {
        asm("v_cvt_pk_bf16_f32 %0, %1, %2" : "=v"(pkw1[pj][0]) : "v"(d1[pj][0]), "v"(d1[pj][1]));
        asm("v_cvt_pk_bf16_f32 %0, %1, %2" : "=v"(pkw1[pj][1]) : "v"(d1[pj][2]), "v"(d1[pj][3]));
    }

    f32x4 oacc0[4];
#pragma unroll
    for (int dj = 0; dj < 4; dj++) oacc0[dj] = f32x4{0.f, 0.f, 0.f, 0.f};
    __builtin_amdgcn_s_setprio(1);
#pragma unroll
    for (int pk = 0; pk < 8; pk++) {
        const int el = (pbase + pk * 32 + g * 8) ^ pxor;
        short8 ap = *(const short8*)&S[el];
#pragma unroll
        for (int dj = 0; dj < 4; dj++) {
            const int d = dj * 16 + lr;
            const int gr = d * 32 + ((pk * 4 + g) ^ (d & 15));
            short8 bv = *(const short8*)&S[16384 + gr * 8];
            oacc0[dj] = mfma16(ap, bv, oacc0[dj]);
        }
    }
    __builtin_amdgcn_s_setprio(0);

#pragma unroll
    for (int pj = 0; pj < 16; pj++) {
        const int el = (pbase + pj * 16 + g * 4) ^ pxor;
        uint2 u; u.x = pkw1[pj][0]; u.y = pkw1[pj][1];
        *(uint2*)&S[el] = u;
    }

    f32x4 oacc1[4];
#pragma unroll
    for (int dj = 0; dj < 4; dj++) oacc1[dj] = f32x4{0.f, 0.f, 0.f, 0.f};
    __builtin_amdgcn_s_setprio(1);
#pragma unroll
    for (int pk = 0; pk < 8; pk++) {
        const int el = (pbase + pk * 32 + g * 8) ^ pxor;
        short8 ap = *(const short8*)&S[el];
#pragma unroll
        for (int dj = 0; dj < 4; dj++) {
            const int d = dj * 16 + lr;
            const int gr = d * 32 + ((pk * 4 + g) ^ (d & 15));
            short8 bv = *(const short8*)&S[16384 + gr * 8];
            oacc1[dj] = mfma16(ap, bv, oacc1[dj]);
        }
    }
    __builtin_amdgcn_s_setprio(0);

    bf16u* Ob0 = O + (mrow + g * 4) * 1024 + h * 64 + lr;
#pragma unroll
    for (int dj = 0; dj < 4; dj++)
#pragma unroll
        for (int r = 0; r < 4; r++)
            Ob0[(size_t)r * 1024 + dj * 16] = f2bf(oacc0[dj][r] * invO0[r]);
    bf16u* Ob1 = Ob0 + (size_t)64 * 1024;
#pragma unroll
    for (int dj = 0; dj < 4; dj++)
#pragma unroll
        for (int r = 0; r < 4; r++)
            Ob1[(size_t)r * 1024 + dj * 16] = f2bf(oacc1[dj][r] * invO1[r]);
}

extern "C" void kernel_launch(void* const* d_in, const int* in_sizes, int n_in,
                              void* d_out, int out_size, void* d_ws, size_t ws_size,
                              hipStream_t stream) {
    const float* x    = (const float*)d_in[0];
    const float* Wqkv = (const float*)d_in[1];
    const float* We   = (const float*)d_in[2];
    const float* be   = (const float*)d_in[3];
    const float* Wo   = (const float*)d_in[4];
    const float* bo   = (const float*)d_in[5];
    float* out = (float*)d_out;

    char* w = (char*)d_ws;
    bf16u* Qbf  = (bf16u*)(w);                              // 67108864
    bf16u* Obuf = (bf16u*)(w + 67108864ull);                // 67108864
    bf16u* Wqb  = (bf16u*)(w + 134217728ull);               // 6291456 (Wq|Wk|Wv stacked)
    bf16u* Web  = (bf16u*)(w + 140509184ull);               // 2097152
    bf16u* Wob  = (bf16u*)(w + 142606336ull);               // 2097152
    bf16u* EXb  = (bf16u*)(w + 144703488ull);               // 4194304 -> total 148897792
    if (ws_size < 148897792ull) return;

    // d_out (128MB) staging timeline (same as round 5).
    bf16u* Xbf = (bf16u*)d_out;
    bf16u* XT  = Xbf + 33554432ull;
    float* EXpart = (float*)d_out;
    bf16u* kpb = Xbf;
    bf16u* vpb = Xbf + 2097152ull;

    cvt_transpose_x<<<dim3(16, 64, 8), 256, 0, stream>>>(x, Xbf, XT);
    cvt_kernel<<<768, 256, 0, stream>>>(Wqkv, Wqb, 3145728 / 4);
    cvt_kernel<<<256, 256, 0, stream>>>(We,   Web, 1048576 / 4);
    cvt_kernel<<<256, 256, 0, stream>>>(Wo,   Wob, 1048576 / 4);

    // Q = X @ Wq^T : [32768][1024], 8-phase 256^2, grid 128*4 = 512 (div 8)
    gemm8p<0><<<512, 512, 0, stream>>>(Xbf, Wqb, nullptr, Qbf, 1024);
    // EX split-K: partial[ks][b][256][1024] fp32
    gemm_ex_splitk<<<dim3(8, 2, 32), 256, 0, stream>>>(Web, XT, EXpart);
    reduce4_cvt<<<2048, 256, 0, stream>>>(EXpart, EXb);
    // [kp|vpT]_b = EX_b @ [Wk|Wv]^T + be
    gemm_kpv<<<dim3(16, 2, 8), 256, 0, stream>>>(EXb, Wqb + (size_t)1024 * 1024, be, kpb, vpb);

    attn_kernel<<<dim3(32, 128), 256, 0, stream>>>(Qbf, kpb, vpb, Obuf);
    // out = O @ Wo^T + bo : fp32, 8-phase 256^2
    gemm8p<1><<<512, 512, 0, stream>>>(Obuf, Wob, bo, out, 1024);
}

// Round 14
// 340.567 us; speedup vs baseline: 1.0035x; 1.0035x over previous
//
#include <hip/hip_runtime.h>
#include <hip/hip_bf16.h>

// Linformer attention, MI355X.
//   EX_b = We @ X_b          (split-K=4, fp32 partials + reduce, 2-phase core)
//   [kp|vpT]_b = EX_b @ [Wk|Wv]^T + be   (fused GEMM, dual-layout epilogue)
//   Q = X @ Wq^T  (gemm8p: 256^2 8-phase counted-vmcnt); attn fused
//   (4 strips x 128 rows per block, Vs staged once); out = O @ Wo^T + bo.
// B=8, N=4096, DIM=1024, H=16, DH=64, P=256.

typedef unsigned short bf16u;
typedef __attribute__((ext_vector_type(8))) short short8;   // 8 bf16 in 4 VGPRs
typedef __attribute__((ext_vector_type(4))) float f32x4;

__device__ __forceinline__ unsigned short f2bf(float f) {
    unsigned u = __float_as_uint(f);
    u += 0x7FFF + ((u >> 16) & 1);          // round-to-nearest-even
    return (unsigned short)(u >> 16);
}

__device__ __forceinline__ f32x4 mfma16(short8 a, short8 b, f32x4 c) {
    return __builtin_amdgcn_mfma_f32_16x16x32_bf16(a, b, c, 0, 0, 0);
}

#define AS1 __attribute__((address_space(1)))
#define AS3 __attribute__((address_space(3)))

// ---------------------------------------------------------------- fp32 -> bf16
__global__ void cvt_kernel(const float* __restrict__ in, bf16u* __restrict__ out, int n4) {
    int i = blockIdx.x * blockDim.x + threadIdx.x;
    int stride = gridDim.x * blockDim.x;
    for (int j = i; j < n4; j += stride) {
        float4 v = ((const float4*)in)[j];
        union { bf16u s[4]; uint2 u; } o;
        o.s[0] = f2bf(v.x); o.s[1] = f2bf(v.y); o.s[2] = f2bf(v.z); o.s[3] = f2bf(v.w);
        ((uint2*)out)[j] = o.u;
    }
}

// ------------------------- fused cvt + 64x64 tiled transpose of x ------------
__global__ __launch_bounds__(256) void cvt_transpose_x(const float* __restrict__ x,
                                                       bf16u* __restrict__ Xbf,
                                                       bf16u* __restrict__ XT) {
    __shared__ bf16u T[64][72];                  // [c-local][n-local], pad 8
    const int b = blockIdx.z;
    const int n0 = blockIdx.y * 64, c0 = blockIdx.x * 64;
    const int t = threadIdx.x;
    const int cx = t & 15, ry = t >> 4;
#pragma unroll
    for (int p = 0; p < 4; p++) {
        const int nn = p * 16 + ry;
        const size_t g = ((size_t)b * 4096 + n0 + nn) * 1024 + c0 + cx * 4;
        float4 v = *(const float4*)&x[g];
        union { bf16u s[4]; uint2 u; } o;
        o.s[0] = f2bf(v.x); o.s[1] = f2bf(v.y); o.s[2] = f2bf(v.z); o.s[3] = f2bf(v.w);
        *(uint2*)&Xbf[g] = o.u;
#pragma unroll
        for (int j = 0; j < 4; j++) T[cx * 4 + j][nn] = o.s[j];
    }
    __syncthreads();
    const int cc = t >> 2, ch = t & 3;
#pragma unroll
    for (int j = 0; j < 2; j++) {
        const int nch = ch + j * 4;
        short8 vv = *(const short8*)&T[cc][nch * 8];
        *(short8*)&XT[((size_t)b * 1024 + c0 + cc) * 4096 + n0 + nch * 8] = vv;
    }
}

// --------------------- 128x128 / BK=64 2-phase double-buffered GEMM core
__device__ __forceinline__ void gemm_core2(const bf16u* __restrict__ Ablk, int ldA,
                                           const bf16u* __restrict__ Bblk, int ldB,
                                           int Kiter, f32x4 (&acc)[4][4]) {
    __shared__ __align__(16) bf16u As[2][8192];
    __shared__ __align__(16) bf16u Bs[2][8192];
    const int t = threadIdx.x;
    const int wave = t >> 6, lane = t & 63;
    const int wm = (wave >> 1) * 64, wn = (wave & 1) * 64;
    const int lr = lane & 15, g4 = lane >> 4;

    auto STAGE = [&](int buf, int kt) {
#pragma unroll
        for (int i = 0; i < 4; i++) {
            const int c = i * 256 + t;                 // granule 0..1023
            const int row = c >> 3, gp = c & 7;
            const int col = kt * 64 + ((gp ^ (row & 7)) << 3);
            __builtin_amdgcn_global_load_lds(
                (const AS1 unsigned*)(Ablk + (size_t)row * ldA + col),
                (AS3 unsigned*)(&As[buf][c * 8]), 16, 0, 0);
            __builtin_amdgcn_global_load_lds(
                (const AS1 unsigned*)(Bblk + (size_t)row * ldB + col),
                (AS3 unsigned*)(&Bs[buf][c * 8]), 16, 0, 0);
        }
    };

    const int nkt = Kiter >> 6;
    STAGE(0, 0);
    __syncthreads();
    for (int kt = 0; kt < nkt; kt++) {
        const int buf = kt & 1;
        if (kt + 1 < nkt) STAGE(buf ^ 1, kt + 1);
        short8 a[4][2], b[4][2];
#pragma unroll
        for (int mi = 0; mi < 4; mi++) {
            const int row = wm + mi * 16 + lr;
#pragma unroll
            for (int ks = 0; ks < 2; ks++) {
                const int gp = (ks * 4 + g4) ^ (row & 7);
                a[mi][ks] = *(const short8*)&As[buf][row * 64 + gp * 8];
            }
        }
#pragma unroll
        for (int ni = 0; ni < 4; ni++) {
            const int row = wn + ni * 16 + lr;
#pragma unroll
            for (int ks = 0; ks < 2; ks++) {
                const int gp = (ks * 4 + g4) ^ (row & 7);
                b[ni][ks] = *(const short8*)&Bs[buf][row * 64 + gp * 8];
            }
        }
#pragma unroll
        for (int ks = 0; ks < 2; ks++)
#pragma unroll
            for (int mi = 0; mi < 4; mi++)
#pragma unroll
                for (int ni = 0; ni < 4; ni++)
                    acc[mi][ni] = mfma16(a[mi][ks], b[ni][ks], acc[mi][ni]);
        __syncthreads();
    }
}

// ---------------------- EX split-K: partial[ks][b][p][c] (fp32), K-slice 1024
__global__ __launch_bounds__(256, 2) void gemm_ex_splitk(const bf16u* __restrict__ We,
                                                         const bf16u* __restrict__ XT,
                                                         float* __restrict__ Cpart) {
    const int bn = blockIdx.x, bm = blockIdx.y;
    const int bz = blockIdx.z >> 2, ks = blockIdx.z & 3;
    f32x4 acc[4][4];
#pragma unroll
    for (int i = 0; i < 4; i++)
#pragma unroll
        for (int j = 0; j < 4; j++) acc[i][j] = f32x4{0.f, 0.f, 0.f, 0.f};

    gemm_core2(We + (size_t)bm * 128 * 4096 + ks * 1024, 4096,
               XT + ((size_t)bz * 1024 + bn * 128) * 4096 + ks * 1024, 4096,
               1024, acc);

    const int lane = threadIdx.x & 63, wave = threadIdx.x >> 6;
    const int wm = (wave >> 1) * 64, wn = (wave & 1) * 64;
    const int lr = lane & 15, lg = (lane >> 4) * 4;
    float* Cp = Cpart + (size_t)(ks * 8 + bz) * 256 * 1024;
#pragma unroll
    for (int ni = 0; ni < 4; ni++) {
        const int col = bn * 128 + wn + ni * 16 + lr;
#pragma unroll
        for (int mi = 0; mi < 4; mi++) {
#pragma unroll
            for (int r = 0; r < 4; r++) {
                const int row = bm * 128 + wm + mi * 16 + lg + r;
                Cp[(size_t)row * 1024 + col] = acc[mi][ni][r];
            }
        }
    }
}

// -------------------- reduce 4 fp32 partials -> bf16 EX (2M elements)
__global__ __launch_bounds__(256) void reduce4_cvt(const float* __restrict__ P,
                                                   bf16u* __restrict__ out) {
    const int j = blockIdx.x * blockDim.x + threadIdx.x;
    const float4* p = (const float4*)P;
    float4 s0 = p[j], s1 = p[j + 524288], s2 = p[j + 1048576], s3 = p[j + 1572864];
    union { bf16u s[4]; uint2 u; } o;
    o.s[0] = f2bf((s0.x + s1.x) + (s2.x + s3.x));
    o.s[1] = f2bf((s0.y + s1.y) + (s2.y + s3.y));
    o.s[2] = f2bf((s0.z + s1.z) + (s2.z + s3.z));
    o.s[3] = f2bf((s0.w + s1.w) + (s2.w + s3.w));
    ((uint2*)out)[j] = o.u;
}

// ----------- fused kp/vpT GEMM: Y_b = EX_b @ [Wk|Wv]^T + be, dual epilogue
__global__ __launch_bounds__(256, 2) void gemm_kpv(const bf16u* __restrict__ EX,
                                                   const bf16u* __restrict__ Wkv,
                                                   const float* __restrict__ be,
                                                   bf16u* __restrict__ kp,
                                                   bf16u* __restrict__ vpT) {
    const int bn = blockIdx.x, bm = blockIdx.y, bz = blockIdx.z;
    f32x4 acc[4][4];
#pragma unroll
    for (int i = 0; i < 4; i++)
#pragma unroll
        for (int j = 0; j < 4; j++) acc[i][j] = f32x4{0.f, 0.f, 0.f, 0.f};

    gemm_core2(EX + (size_t)bz * 256 * 1024 + (size_t)bm * 128 * 1024, 1024,
               Wkv + (size_t)bn * 128 * 1024, 1024, 1024, acc);

    const int lane = threadIdx.x & 63, wave = threadIdx.x >> 6;
    const int wm = (wave >> 1) * 64, wn = (wave & 1) * 64;
    const int lr = lane & 15, lg = (lane >> 4) * 4;
    bf16u* kpB = kp + (size_t)bz * 256 * 1024;
    bf16u* vpB = vpT + (size_t)bz * 1024 * 256;
    const int ebase = bn * 128 + wn;
#pragma unroll
    for (int ni = 0; ni < 4; ni++) {
        const int col = ebase + ni * 16 + lr;
        const int region = (ebase + ni * 16) >> 10;
#pragma unroll
        for (int mi = 0; mi < 4; mi++) {
            const int p0 = bm * 128 + wm + mi * 16 + lg;
            if (region == 0) {
#pragma unroll
                for (int r = 0; r < 4; r++)
                    kpB[(size_t)(p0 + r) * 1024 + col] = f2bf(acc[mi][ni][r] + be[p0 + r]);
            } else {
                const int d = col - 1024;
                union { bf16u s[4]; uint2 u; } o;
#pragma unroll
                for (int r = 0; r < 4; r++) o.s[r] = f2bf(acc[mi][ni][r] + be[p0 + r]);
                *(uint2*)&vpB[(size_t)d * 256 + p0] = o.u;
            }
        }
    }
}

// -------- 256x256 / BK=64 / 8-wave (2M x 4N), 8-phase counted-vmcnt GEMM
template<int MODE>
__global__ __launch_bounds__(512, 2) void gemm8p(const bf16u* __restrict__ A,
                                                 const bf16u* __restrict__ Bt,
                                                 const float* __restrict__ bias,
                                                 void* __restrict__ Cout,
                                                 int K) {
    __shared__ __align__(16) bf16u L[2][32768];   // [buf]: A[256][64] | B[256][64]

    const int nwg = gridDim.x;                    // multiple of 8
    const int bid = blockIdx.x;
    const int logical = (bid & 7) * (nwg >> 3) + (bid >> 3);
    const int bn = logical & 3, bm = logical >> 2;

    const bf16u* Ablk = A + (size_t)bm * 256 * K;
    const bf16u* Bblk = Bt + (size_t)bn * 256 * K;

    const int t = threadIdx.x;
    const int wid = t >> 6, lane = t & 63;
    const int wm = (wid >> 2) * 128, wn = (wid & 3) * 64;   // per-wave 128x64 out
    const int lr = lane & 15, g4 = lane >> 4;

    f32x4 acc[8][4];
#pragma unroll
    for (int i = 0; i < 8; i++)
#pragma unroll
        for (int j = 0; j < 4; j++) acc[i][j] = f32x4{0.f, 0.f, 0.f, 0.f};

    auto STAGE = [&](int buf, int which, int half, int kt) {
#pragma unroll
        for (int i = 0; i < 2; i++) {
            const int c = i * 512 + t;
            const int row = half * 128 + (c >> 3);
            const int gp = c & 7;
            const int col = kt * 64 + ((gp ^ (row & 7)) << 3);
            const bf16u* src = (which ? Bblk : Ablk) + (size_t)row * K + col;
            __builtin_amdgcn_global_load_lds((const AS1 unsigned*)src,
                (AS3 unsigned*)(&L[buf][which * 16384 + half * 8192 + c * 8]), 16, 0, 0);
        }
    };

    short8 aF[4][2], bE[2][2], bO[2][2];
    auto LDA = [&](int buf, int mq) {
#pragma unroll
        for (int mi = 0; mi < 4; mi++) {
            const int row = wm + mq * 64 + mi * 16 + lr;
#pragma unroll
            for (int ks = 0; ks < 2; ks++) {
                const int gp = (ks * 4 + g4) ^ (row & 7);
                aF[mi][ks] = *(const short8*)&L[buf][row * 64 + gp * 8];
            }
        }
    };
    auto LDB = [&](int buf, int nq, short8 (&bF)[2][2]) {
#pragma unroll
        for (int ni = 0; ni < 2; ni++) {
            const int row = wn + nq * 32 + ni * 16 + lr;
#pragma unroll
            for (int ks = 0; ks < 2; ks++) {
                const int gp = (ks * 4 + g4) ^ (row & 7);
                bF[ni][ks] = *(const short8*)&L[buf][16384 + row * 64 + gp * 8];
            }
        }
    };
    auto MM = [&](int mq, int nq, short8 (&bF)[2][2]) {
        __builtin_amdgcn_s_setprio(1);
#pragma unroll
        for (int mi = 0; mi < 4; mi++)
#pragma unroll
            for (int nj = 0; nj < 2; nj++)
#pragma unroll
                for (int ks = 0; ks < 2; ks++)
                    acc[mq * 4 + mi][nq * 2 + nj] =
                        mfma16(aF[mi][ks], bF[nj][ks], acc[mq * 4 + mi][nq * 2 + nj]);
        __builtin_amdgcn_s_setprio(0);
    };
    auto BAR = [&]() {
        asm volatile("" ::: "memory");
        __builtin_amdgcn_s_barrier();
        asm volatile("" ::: "memory");
    };
    auto LGKM0 = [&]() {
        asm volatile("s_waitcnt lgkmcnt(0)" ::: "memory");
        __builtin_amdgcn_sched_barrier(0);
    };

    const int nkt = K >> 6;
    const int niter = nkt >> 1;

    STAGE(0, 0, 0, 0); STAGE(0, 0, 1, 0); STAGE(0, 1, 0, 0); STAGE(0, 1, 1, 0);
    STAGE(1, 0, 0, 1); STAGE(1, 0, 1, 1); STAGE(1, 1, 0, 1); STAGE(1, 1, 1, 1);
    asm volatile("s_waitcnt vmcnt(8)" ::: "memory");
    BAR();

    for (int it = 0; it < niter; it++) {
        const int kt1 = 2 * it + 1, kt2 = 2 * it + 2, kt3 = 2 * it + 3;
        const bool p123 = (it > 0), s4 = (kt2 < nkt), s8 = (kt3 < nkt);

        LDA(0, 0); LDB(0, 0, bE);
        if (p123) STAGE(1, 0, 1, kt1);
        asm volatile("s_waitcnt lgkmcnt(8)" ::: "memory");
        BAR(); LGKM0();
        MM(0, 0, bE);
        BAR();
        LDB(0, 1, bO);
        if (p123) STAGE(1, 1, 0, kt1);
        BAR(); LGKM0();
        MM(0, 1, bO);
        BAR();
        LDA(0, 1);
        if (p123) STAGE(1, 1, 1, kt1);
        BAR(); LGKM0();
        MM(1, 1, bO);
        BAR();
        if (s4) STAGE(0, 0, 0, kt2);
        MM(1, 0, bE);
        if (s4) asm volatile("s_waitcnt vmcnt(2)" ::: "memory");
        else    asm volatile("s_waitcnt vmcnt(0)" ::: "memory");
        BAR();

        LDA(1, 0); LDB(1, 0, bE);
        if (s4) STAGE(0, 0, 1, kt2);
        asm volatile("s_waitcnt lgkmcnt(8)" ::: "memory");
        BAR(); LGKM0();
        MM(0, 0, bE);
        BAR();
        LDB(1, 1, bO);
        if (s4) STAGE(0, 1, 0, kt2);
        BAR(); LGKM0();
        MM(0, 1, bO);
        BAR();
        LDA(1, 1);
        if (s4) STAGE(0, 1, 1, kt2);
        BAR(); LGKM0();
        MM(1, 1, bO);
        BAR();
        if (s8) STAGE(1, 0, 0, kt3);
        MM(1, 0, bE);
        if (s8) asm volatile("s_waitcnt vmcnt(2)" ::: "memory");
        else    asm volatile("s_waitcnt vmcnt(0)" ::: "memory");
        BAR();
    }

    const int lg = g4 * 4;
    if (MODE == 0) {
        bf16u* C = (bf16u*)Cout;
#pragma unroll
        for (int mi = 0; mi < 8; mi++) {
#pragma unroll
            for (int r = 0; r < 4; r++) {
                const size_t row = (size_t)bm * 256 + wm + mi * 16 + lg + r;
#pragma unroll
                for (int ni = 0; ni < 4; ni++)
                    C[row * 1024 + bn * 256 + wn + ni * 16 + lr] = f2bf(acc[mi][ni][r]);
            }
        }
    } else {
        float* C = (float*)Cout;
        float bv[4];
#pragma unroll
        for (int ni = 0; ni < 4; ni++) bv[ni] = bias[bn * 256 + wn + ni * 16 + lr];
#pragma unroll
        for (int mi = 0; mi < 8; mi++) {
#pragma unroll
            for (int r = 0; r < 4; r++) {
                const size_t row = (size_t)bm * 256 + wm + mi * 16 + lg + r;
#pragma unroll
                for (int ni = 0; ni < 4; ni++)
                    C[row * 1024 + bn * 256 + wn + ni * 16 + lr] = acc[mi][ni][r] + bv[ni];
            }
        }
    }
}

// ---------------------------------------------------- K3: fused attention
// v4: strip-mined. grid (8, B*H); each block owns 512 q-rows as 4 strips of
// 128. Ks/Vs depend only on (b,h): Vs staged ONCE per block; Ks re-staged per
// strip only because the P overlay clobbers it (strips share identical Ks
// data). Per strip: QK^T (2 row-groups/wave, Ks-fragment reuse) -> bar ->
// P0/PV0/P1/PV1 (own-slot WAR, lgkmcnt-ordered) -> store O -> bar ->
// re-stage Ks -> __syncthreads (drains vmcnt). Accumulation order per output
// element identical to round 10 -> absmax must stay exactly 1.4648e-3.
__global__ __launch_bounds__(256, 2) void attn_kernel(const bf16u* __restrict__ Q,
                                                      const bf16u* __restrict__ kp,
                                                      const bf16u* __restrict__ vpT,
                                                      bf16u* __restrict__ O) {
    __shared__ __align__(16) bf16u S[32768];     // [0,16384): Ks / P overlay; [16384,32768): Vs
    const int bh = blockIdx.y, b = bh >> 4, h = bh & 15;
    const int t = threadIdx.x;
    const int wave = t >> 6, lane = t & 63;
    const int lr = lane & 15, g = lane >> 4;
    const size_t mbase = (size_t)b * 4096 + blockIdx.x * 512;

    const bf16u* kpb = kp + ((size_t)b * 256) * 1024 + h * 64;
    const bf16u* vpb = vpT + ((size_t)b * 1024 + h * 64) * 256;

    auto STAGE_K = [&]() {
#pragma unroll
        for (int i = 0; i < 8; i++) {
            const int c = i * 256 + t;
            const int ubase = (i * 256 + wave * 64) * 8;
            const int p = c >> 3, d8 = (c & 7) ^ (p & 7);
            __builtin_amdgcn_global_load_lds(
                (const AS1 unsigned*)(kpb + (size_t)p * 1024 + d8 * 8),
                (AS3 unsigned*)&S[ubase], 16, 0, 0);
        }
    };

    // prologue: Vs once + Ks for strip 0
#pragma unroll
    for (int i = 0; i < 8; i++) {
        const int c = i * 256 + t;
        const int ubase = (i * 256 + wave * 64) * 8;
        const int d = c >> 5, p8 = (c & 31) ^ (d & 15);
        __builtin_amdgcn_global_load_lds(
            (const AS1 unsigned*)(vpb + (size_t)d * 256 + p8 * 8),
            (AS3 unsigned*)&S[16384 + ubase], 16, 0, 0);
    }
    STAGE_K();
    __syncthreads();

    const int pbase = wave * 4096 + lr * 256;
    const int pxor = (lr & 7) << 3;

    for (int s = 0; s < 4; s++) {
        const size_t mrow = mbase + s * 128 + wave * 16;   // G0 rows; G1 = +64

        short8 bq0[2], bq1[2];
        const bf16u* Qb0 = Q + (mrow + lr) * 1024 + h * 64 + g * 8;
        bq0[0] = *(const short8*)&Qb0[0];
        bq0[1] = *(const short8*)&Qb0[32];
        const bf16u* Qb1 = Qb0 + (size_t)64 * 1024;
        bq1[0] = *(const short8*)&Qb1[0];
        bq1[1] = *(const short8*)&Qb1[32];

        // QK^T swapped, Ks fragment shared by both groups
        f32x4 d0[16], d1[16];
#pragma unroll
        for (int pj = 0; pj < 16; pj++) { d0[pj] = f32x4{0.f,0.f,0.f,0.f}; d1[pj] = f32x4{0.f,0.f,0.f,0.f}; }
        __builtin_amdgcn_s_setprio(1);
#pragma unroll
        for (int pj = 0; pj < 16; pj++) {
#pragma unroll
            for (int kk = 0; kk < 2; kk++) {
                const int gr = (pj * 16 + lr) * 8 + ((kk * 4 + g) ^ (lr & 7));
                short8 ak = *(const short8*)&S[gr * 8];
                d0[pj] = mfma16(ak, bq0[kk], d0[pj]);
                d1[pj] = mfma16(ak, bq1[kk], d1[pj]);
            }
        }
        __builtin_amdgcn_s_setprio(0);

        // softmax G0
        float s0 = 0.f;
#pragma unroll
        for (int pj = 0; pj < 16; pj++) {
#pragma unroll
            for (int r = 0; r < 4; r++) {
                float e = __expf(d0[pj][r] * 0.125f);
                d0[pj][r] = e;
                s0 += e;
            }
        }
        s0 += __shfl_xor(s0, 16);
        s0 += __shfl_xor(s0, 32);
        const float inv0 = 1.0f / s0;
        float invO0[4];
#pragma unroll
        for (int r = 0; r < 4; r++) invO0[r] = __shfl(inv0, g * 4 + r);

        unsigned pkw0[16][2];
#pragma unroll
        for (int pj = 0; pj < 16; pj++) {
            asm("v_cvt_pk_bf16_f32 %0, %1, %2" : "=v"(pkw0[pj][0]) : "v"(d0[pj][0]), "v"(d0[pj][1]));
            asm("v_cvt_pk_bf16_f32 %0, %1, %2" : "=v"(pkw0[pj][1]) : "v"(d0[pj][2]), "v"(d0[pj][3]));
        }

        // all waves done reading Ks for this strip -> overlay P
        __syncthreads();

#pragma unroll
        for (int pj = 0; pj < 16; pj++) {
            const int el = (pbase + pj * 16 + g * 4) ^ pxor;
            uint2 u; u.x = pkw0[pj][0]; u.y = pkw0[pj][1];
            *(uint2*)&S[el] = u;
        }

        // softmax G1 (hides under PV0)
        float s1 = 0.f;
#pragma unroll
        for (int pj = 0; pj < 16; pj++) {
#pragma unroll
            for (int r = 0; r < 4; r++) {
                float e = __expf(d1[pj][r] * 0.125f);
                d1[pj][r] = e;
                s1 += e;
            }
        }
        s1 += __shfl_xor(s1, 16);
        s1 += __shfl_xor(s1, 32);
        const float inv1 = 1.0f / s1;
        float invO1[4];
#pragma unroll
        for (int r = 0; r < 4; r++) invO1[r] = __shfl(inv1, g * 4 + r);
        unsigned pkw1[16][2];
#pragma unroll
        for (int pj = 0; pj < 16; pj++) {
            asm("v_cvt_pk_bf16_f32 %0, %1, %2" : "=v"(pkw1[pj][0]) : "v"(d1[pj][0]), "v"(d1[pj][1]));
            asm("v_cvt_pk_bf16_f32 %0, %1, %2" : "=v"(pkw1[pj][1]) : "v"(d1[pj][2]), "v"(d1[pj][3]));
        }

        // PV G0
        f32x4 oacc0[4];
#pragma unroll
        for (int dj = 0; dj < 4; dj++) oacc0[dj] = f32x4{0.f, 0.f, 0.f, 0.f};
        __builtin_amdgcn_s_setprio(1);
#pragma unroll
        for (int pk = 0; pk < 8; pk++) {
            const int el = (pbase + pk * 32 + g * 8) ^ pxor;
            short8 ap = *(const short8*)&S[el];
#pragma unroll
            for (int dj = 0; dj < 4; dj++) {
                const int d = dj * 16 + lr;
                const int gr = d * 32 + ((pk * 4 + g) ^ (d & 15));
                short8 bv = *(const short8*)&S[16384 + gr * 8];
                oacc0[dj] = mfma16(ap, bv, oacc0[dj]);
            }
        }
        __builtin_amdgcn_s_setprio(0);

        // overwrite own P slot with G1 (same-wave WAR ordered via lgkmcnt)
#pragma unroll
        for (int pj = 0; pj < 16; pj++) {
            const int el = (pbase + pj * 16 + g * 4) ^ pxor;
            uint2 u; u.x = pkw1[pj][0]; u.y = pkw1[pj][1];
            *(uint2*)&S[el] = u;
        }

        // PV G1
        f32x4 oacc1[4];
#pragma unroll
        for (int dj = 0; dj < 4; dj++) oacc1[dj] = f32x4{0.f, 0.f, 0.f, 0.f};
        __builtin_amdgcn_s_setprio(1);
#pragma unroll
        for (int pk = 0; pk < 8; pk++) {
            const int el = (pbase + pk * 32 + g * 8) ^ pxor;
            short8 ap = *(const short8*)&S[el];
#pragma unroll
            for (int dj = 0; dj < 4; dj++) {
                const int d = dj * 16 + lr;
                const int gr = d * 32 + ((pk * 4 + g) ^ (d & 15));
                short8 bv = *(const short8*)&S[16384 + gr * 8];
                oacc1[dj] = mfma16(ap, bv, oacc1[dj]);
            }
        }
        __builtin_amdgcn_s_setprio(0);

        // stores (row-matched denominators)
        bf16u* Ob0 = O + (mrow + g * 4) * 1024 + h * 64 + lr;
#pragma unroll
        for (int dj = 0; dj < 4; dj++)
#pragma unroll
            for (int r = 0; r < 4; r++)
                Ob0[(size_t)r * 1024 + dj * 16] = f2bf(oacc0[dj][r] * invO0[r]);
        bf16u* Ob1 = Ob0 + (size_t)64 * 1024;
#pragma unroll
        for (int dj = 0; dj < 4; dj++)
#pragma unroll
            for (int r = 0; r < 4; r++)
                Ob1[(size_t)r * 1024 + dj * 16] = f2bf(oacc1[dj][r] * invO1[r]);

        if (s < 3) {
            // all waves done reading their P (PV complete) -> re-stage Ks
            __syncthreads();
            STAGE_K();
            __syncthreads();            // drains vmcnt: Ks resident for next strip
        }
    }
}

extern "C" void kernel_launch(void* const* d_in, const int* in_sizes, int n_in,
                              void* d_out, int out_size, void* d_ws, size_t ws_size,
                              hipStream_t stream) {
    const float* x    = (const float*)d_in[0];
    const float* Wqkv = (const float*)d_in[1];
    const float* We   = (const float*)d_in[2];
    const float* be   = (const float*)d_in[3];
    const float* Wo   = (const float*)d_in[4];
    const float* bo   = (const float*)d_in[5];
    float* out = (float*)d_out;

    char* w = (char*)d_ws;
    bf16u* Qbf  = (bf16u*)(w);                              // 67108864
    bf16u* Obuf = (bf16u*)(w + 67108864ull);                // 67108864
    bf16u* Wqb  = (bf16u*)(w + 134217728ull);               // 6291456 (Wq|Wk|Wv stacked)
    bf16u* Web  = (bf16u*)(w + 140509184ull);               // 2097152
    bf16u* Wob  = (bf16u*)(w + 142606336ull);               // 2097152
    bf16u* EXb  = (bf16u*)(w + 144703488ull);               // 4194304 -> total 148897792
    if (ws_size < 148897792ull) return;

    // d_out (128MB) staging timeline (same as round 5).
    bf16u* Xbf = (bf16u*)d_out;
    bf16u* XT  = Xbf + 33554432ull;
    float* EXpart = (float*)d_out;
    bf16u* kpb = Xbf;
    bf16u* vpb = Xbf + 2097152ull;

    cvt_transpose_x<<<dim3(16, 64, 8), 256, 0, stream>>>(x, Xbf, XT);
    cvt_kernel<<<768, 256, 0, stream>>>(Wqkv, Wqb, 3145728 / 4);
    cvt_kernel<<<256, 256, 0, stream>>>(We,   Web, 1048576 / 4);
    cvt_kernel<<<256, 256, 0, stream>>>(Wo,   Wob, 1048576 / 4);

    // Q = X @ Wq^T : [32768][1024], 8-phase 256^2, grid 128*4 = 512 (div 8)
    gemm8p<0><<<512, 512, 0, stream>>>(Xbf, Wqb, nullptr, Qbf, 1024);
    // EX split-K: partial[ks][b][256][1024] fp32
    gemm_ex_splitk<<<dim3(8, 2, 32), 256, 0, stream>>>(Web, XT, EXpart);
    reduce4_cvt<<<2048, 256, 0, stream>>>(EXpart, EXb);
    // [kp|vpT]_b = EX_b @ [Wk|Wv]^T + be
    gemm_kpv<<<dim3(16, 2, 8), 256, 0, stream>>>(EXb, Wqb + (size_t)1024 * 1024, be, kpb, vpb);

    attn_kernel<<<dim3(8, 128), 256, 0, stream>>>(Qbf, kpb, vpb, Obuf);
    // out = O @ Wo^T + bo : fp32, 8-phase 256^2
    gemm8p<1><<<512, 512, 0, stream>>>(Obuf, Wob, bo, out, 1024);
}